// Round 13
// baseline (146.072 us; speedup 1.0000x reference)
//
#include <hip/hip_runtime.h>
#include <stdint.h>

// SSD multibox head. Round 13: R11 base (256-thread GEMM blocks, overlapped
// 2-phase double-buffer, QS=36, bf16 ybuf partials, tile-transpose scatter).
// Change: MFMA retiled to 32x32x16 (wave tile 64x64 = 2x2 of 32x32; 16 MFMA
// + 16 ds_read_b128 per K-step per wave) — same FLOPs, -17% MFMA issue
// cycles, 32x32 unit runs at higher rate (2382 vs 2075 TF ubench).

#define NTH 256
#define ATOT 8732
#define LOCTOT 279424       // 8*8732*4
#define QS 36               // K-steps per block, uniform across scales
#define TOTOUT 5937760      // 8*8732*85
#define MR 8                // ybuf rows per scatter block

typedef short short8 __attribute__((ext_vector_type(8)));
typedef unsigned short ushort8 __attribute__((ext_vector_type(8)));
typedef float f32x16 __attribute__((ext_vector_type(16)));

__device__ __forceinline__ unsigned short f2bf(float f) {
  unsigned u = __float_as_uint(f);
  u += 0x7fffu + ((u >> 16) & 1u);   // RNE
  return (unsigned short)(u >> 16);
}

__device__ __forceinline__ float bf2f(unsigned short b) {
  return __uint_as_float((unsigned)b << 16);
}

__device__ __forceinline__ void gload_lds16(const void* g, void* l) {
  __builtin_amdgcn_global_load_lds(
      (const __attribute__((address_space(1))) unsigned int*)g,
      (__attribute__((address_space(3))) unsigned int*)l, 16, 0, 0);
}

// ---------------- merged prep: x-transpose blocks then w-repack blocks ------
struct PXs { const float* x; unsigned short* xh; int C, HWp, ptiles, boff; };
struct PWs { const float *lw, *cw; unsigned short* wp; int C, lC, Nloc, Ntot, Npad, Kp; size_t tbase; };
struct PREP { PXs x[6]; PWs w[6]; int pxb; };

__global__ __launch_bounds__(NTH) void prep_all(PREP P) {
  __shared__ float T[64][65];
  const int tid = threadIdx.x;
  if ((int)blockIdx.x < P.pxb) {
    const int bid = blockIdx.x;
    int e = 0;
    #pragma unroll
    for (int i = 1; i < 6; ++i) if (bid >= P.x[i].boff) e = i;
    const PXs sp = P.x[e];
    const int local = bid - sp.boff;
    const int p64 = local % sp.ptiles;
    const int t2  = local / sp.ptiles;
    const int Cq  = sp.C >> 6;
    const int c64 = t2 % Cq;
    const int bb  = t2 / Cq;

    const int p0 = p64 << 6;
    const float* xs = sp.x + (size_t)(bb * sp.C + (c64 << 6)) * sp.HWp;
    const int tx = tid & 63, ty = tid >> 6;
    const int p = p0 + tx;
    const bool pok = p < sp.HWp;
    #pragma unroll
    for (int j = 0; j < 16; ++j) {
      int c = ty + (j << 2);
      T[c][tx] = pok ? xs[(size_t)c * sp.HWp + p] : 0.f;
    }
    __syncthreads();
    const int pl = tid >> 2, cs = (tid & 3) << 4;
    const int pg = p0 + pl;
    if (pg < sp.HWp) {
      unsigned short* dst = sp.xh + ((size_t)bb * sp.HWp + pg) * sp.C + (c64 << 6) + cs;
      short8 v0, v1;
      #pragma unroll
      for (int j = 0; j < 8; ++j) {
        v0[j] = (short)f2bf(T[cs + j][pl]);
        v1[j] = (short)f2bf(T[cs + 8 + j][pl]);
      }
      *(short8*)dst = v0;
      *(short8*)(dst + 8) = v1;
    }
  } else {
    const size_t g = (size_t)(blockIdx.x - P.pxb) * NTH + tid;
    int e = 0;
    #pragma unroll
    for (int i = 1; i < 6; ++i) if (g >= P.w[i].tbase) e = i;
    const PWs sp = P.w[e];
    const size_t local = g - sp.tbase;
    const int ci = (int)(local & (size_t)(sp.C - 1));
    const int co = (int)(local >> sp.lC);
    if (co >= sp.Npad) return;
    unsigned short* dst = sp.wp + (size_t)co * sp.Kp + ci;
    if (co >= sp.Ntot) {
      #pragma unroll
      for (int r = 0; r < 9; ++r) dst[(size_t)r * sp.C] = 0;
      return;
    }
    const float* wr = (co < sp.Nloc)
        ? (sp.lw + ((size_t)co * sp.C + ci) * 9)
        : (sp.cw + ((size_t)(co - sp.Nloc) * sp.C + ci) * 9);
    float v[9];
    #pragma unroll
    for (int r = 0; r < 9; ++r) v[r] = wr[r];
    #pragma unroll
    for (int r = 0; r < 9; ++r) dst[(size_t)r * sp.C] = f2bf(v[r]);
  }
}

// ---------------- main GEMM: 256 threads, 4 waves, 32x32x16 MFMA ------------
struct SG {
  const unsigned short *xh, *wp;
  unsigned short* yb;              // [S][M][Npad] bf16 partials
  int H, W, HWp, C, lCq, Cq, Kp, M, Npad, mtiles, lgS, boff;
};
struct AG { SG s[6]; const char* zeros; int gq, gr; };

__global__ __launch_bounds__(NTH) void mbox_gemm(AG P) {
  __shared__ __align__(16) unsigned short A_s[2][128 * 64];
  __shared__ __align__(16) unsigned short B_s[2][128 * 64];

  const int bid = blockIdx.x;
  const int xcd = bid & 7, sidx = bid >> 3;
  const int g = (xcd < P.gr) ? xcd * (P.gq + 1) + sidx
                             : P.gr * (P.gq + 1) + (xcd - P.gr) * P.gq + sidx;

  int e = 0;
  #pragma unroll
  for (int i = 1; i < 6; ++i) if (g >= P.s[i].boff) e = i;
  const SG sp = P.s[e];
  const int gl = g - sp.boff;
  const int ks = gl & ((1 << sp.lgS) - 1);
  const int t2 = gl >> sp.lgS;
  const int mtile = t2 % sp.mtiles;
  const int ntile = t2 / sp.mtiles;

  const int tid = threadIdx.x, lane = tid & 63, wv = tid >> 6;
  const int wm = wv >> 1, wn = wv & 1;
  const int swz = ((lane & 7) ^ (lane >> 3)) << 4;
  const int rsub = lane >> 3;

  int bA[4], hA[4], wA[4]; bool mok[4];
  #pragma unroll
  for (int i = 0; i < 4; ++i) {
    int row = (wv << 5) + (i << 3) + rsub;
    int mg = mtile * 128 + row;
    bool ok = mg < sp.M;
    int mc = ok ? mg : 0;
    int bb = mc / sp.HWp; int p = mc - bb * sp.HWp;
    int hh = p / sp.W;    int ww = p - hh * sp.W;
    bA[i] = bb; hA[i] = hh; wA[i] = ww; mok[i] = ok;
  }

  const int q0 = ks * QS, q1 = q0 + QS;

  const char* curB[4];
  #pragma unroll
  for (int i = 0; i < 4; ++i) {
    int row = (wv << 5) + (i << 3) + rsub;
    int nrow = ntile * 128 + row;
    curB[i] = (const char*)(sp.wp + (size_t)nrow * sp.Kp + (size_t)q0 * 64) + swz;
  }

  const char* curA[4];
  auto setA = [&](int rr, int cq0) {
    int d3 = rr / 3; int dh = d3 - 1, dw = rr - d3 * 3 - 1;
    #pragma unroll
    for (int i = 0; i < 4; ++i) {
      int hh = hA[i] + dh, ww = wA[i] + dw;
      bool ok = mok[i] & ((unsigned)hh < (unsigned)sp.H) & ((unsigned)ww < (unsigned)sp.W);
      const unsigned short* base = ok
          ? sp.xh + (((size_t)bA[i] * sp.H + hh) * sp.W + ww) * sp.C + (cq0 << 6)
          : (const unsigned short*)P.zeros;
      curA[i] = (const char*)base + swz;
    }
  };

  auto stage = [&](int buf) {
    char* As = (char*)&A_s[buf][0];
    char* Bs = (char*)&B_s[buf][0];
    #pragma unroll
    for (int i = 0; i < 4; ++i)
      gload_lds16(curA[i], As + ((wv << 5) + (i << 3)) * 128);
    #pragma unroll
    for (int i = 0; i < 4; ++i)
      gload_lds16(curB[i], Bs + ((wv << 5) + (i << 3)) * 128);
  };

  f32x16 acc00 = {}, acc01 = {}, acc10 = {}, acc11 = {};
  const int la = lane & 31;

  setA(q0 >> sp.lCq, q0 & (sp.Cq - 1));
  stage(0);
  #pragma unroll
  for (int i = 0; i < 4; ++i) { curA[i] += 128; curB[i] += 128; }

  int cur = 0;
  for (int q = q0; q < q1; ++q) {
    __syncthreads();
    if (q + 1 < q1) {
      if (((q + 1) & (sp.Cq - 1)) == 0) setA((q + 1) >> sp.lCq, 0);
      stage(cur ^ 1);
      #pragma unroll
      for (int i = 0; i < 4; ++i) { curA[i] += 128; curB[i] += 128; }
    }
    const char* As = (const char*)&A_s[cur][0];
    const char* Bs = (const char*)&B_s[cur][0];
    #pragma unroll
    for (int t = 0; t < 4; ++t) {     // 4 k-subs of K=16
      const int kb = (t << 5) + ((lane >> 5) << 4);   // byte offset
      const int r0 = (wm << 6) + la;
      const int r1 = r0 + 32;                          // (r1&7)==(r0&7)
      const int c0 = (wn << 6) + la;
      const int c1 = c0 + 32;
      short8 a0 = *(const short8*)(As + r0 * 128 + (kb ^ ((r0 & 7) << 4)));
      short8 a1 = *(const short8*)(As + r1 * 128 + (kb ^ ((r0 & 7) << 4)));
      short8 b0 = *(const short8*)(Bs + c0 * 128 + (kb ^ ((c0 & 7) << 4)));
      short8 b1 = *(const short8*)(Bs + c1 * 128 + (kb ^ ((c0 & 7) << 4)));
      acc00 = __builtin_amdgcn_mfma_f32_32x32x16_bf16(a0, b0, acc00, 0, 0, 0);
      acc01 = __builtin_amdgcn_mfma_f32_32x32x16_bf16(a0, b1, acc01, 0, 0, 0);
      acc10 = __builtin_amdgcn_mfma_f32_32x32x16_bf16(a1, b0, acc10, 0, 0, 0);
      acc11 = __builtin_amdgcn_mfma_f32_32x32x16_bf16(a1, b1, acc11, 0, 0, 0);
    }
    cur ^= 1;
  }

  // epilogue: dense coalesced bf16 store of partial tile into ybuf[ks]
  // C/D map (m74/m101): col=lane&31, row=(reg&3)+8*(reg>>2)+4*(lane>>5)
  unsigned short* yb = sp.yb + (size_t)ks * sp.M * sp.Npad;
  const int rb4 = (lane >> 5) << 2;
  const int nc0 = ntile * 128 + (wn << 6) + la;
  const int nc1 = nc0 + 32;
  #pragma unroll
  for (int r = 0; r < 16; ++r) {
    const int mrow = (r & 3) + ((r >> 2) << 3) + rb4;
    const int mg0 = mtile * 128 + (wm << 6) + mrow;
    const int mg1 = mg0 + 32;
    if (mg0 < sp.M) {
      yb[(size_t)mg0 * sp.Npad + nc0] = f2bf(acc00[r]);
      yb[(size_t)mg0 * sp.Npad + nc1] = f2bf(acc01[r]);
    }
    if (mg1 < sp.M) {
      yb[(size_t)mg1 * sp.Npad + nc0] = f2bf(acc10[r]);
      yb[(size_t)mg1 * sp.Npad + nc1] = f2bf(acc11[r]);
    }
  }
}

// ---------------- scatter: tile-staged transpose (bf16 partials) ------------
struct SC2s { const unsigned short* yb; const float *lb, *cb; int HW, nb, S, Npad, M, abase, boff; };
struct SC2 { SC2s s[6]; };

__global__ __launch_bounds__(NTH) void mbox_scatter(SC2 P, float* __restrict__ out) {
  __shared__ float T[MR * 512];     // summed tile, row stride = Npad (<=512)
  __shared__ float LB[32], CB[512];
  const int bid = blockIdx.x;
  int e = 0;
  #pragma unroll
  for (int i = 1; i < 6; ++i) if (bid >= P.s[i].boff) e = i;
  const SC2s sp = P.s[e];
  const int m0 = (bid - sp.boff) * MR;
  const int tid = threadIdx.x;
  const int HW = sp.HW, nb = sp.nb, Npad = sp.Npad;
  const int nb4v = nb * 4;

  for (int i = tid; i < nb4v; i += NTH) LB[i] = sp.lb[i];
  for (int i = tid; i < nb * 81; i += NTH) CB[i] = sp.cb[i];

  const int np8 = Npad >> 3;
  const int tot8 = MR * np8;
  const size_t dstride8 = (size_t)sp.M * np8;      // in ushort8 units
  const ushort8* yb8 = (const ushort8*)sp.yb + (size_t)m0 * np8;
  for (int idx = tid; idx < tot8; idx += NTH) {
    float v[8] = {0.f, 0.f, 0.f, 0.f, 0.f, 0.f, 0.f, 0.f};
    const ushort8* p = yb8 + idx;
    for (int k = 0; k < sp.S; ++k) {
      ushort8 w = *p; p += dstride8;
      #pragma unroll
      for (int j = 0; j < 8; ++j) v[j] += bf2f(w[j]);
    }
    #pragma unroll
    for (int j = 0; j < 8; ++j) T[(idx << 3) + j] = v[j];
  }
  __syncthreads();

  if (tid < MR * nb) {
    const int mloc = tid / nb, rb = tid - (tid / nb) * nb;
    const int m = m0 + mloc;
    const int b = m / HW, p = m - b * HW;
    const int aidx = sp.abase + rb * HW + p;
    float4 v;
    #pragma unroll
    for (int ii = 0; ii < 4; ++ii)
      (&v.x)[ii] = T[mloc * Npad + ii * nb + rb] + LB[ii * nb + rb];
    ((float4*)out)[(size_t)b * ATOT + aidx] = v;
  }

  const int totc = MR * nb * 81;
  float* outc = out + LOCTOT;
  for (int f = tid; f < totc; f += NTH) {
    const int ii = f % 81;
    const int gg = f / 81;
    const int rb = gg % nb;
    const int mloc = gg / nb;
    const int m = m0 + mloc;
    const int b = m / HW, p = m - b * HW;
    const int aidx = sp.abase + rb * HW + p;
    const int c = ii * nb + rb;
    outc[((size_t)b * ATOT + aidx) * 81 + ii] = T[mloc * Npad + nb4v + c] + CB[c];
  }
}

// ---------------- host ------------------------------------------------------
extern "C" void kernel_launch(void* const* d_in, const int* in_sizes, int n_in,
                              void* d_out, int out_size, void* d_ws, size_t ws_size,
                              hipStream_t stream) {
  static const int CH[6]  = {512, 1024, 512, 256, 256, 256};
  static const int HH[6]  = {38, 19, 10, 5, 3, 1};
  static const int NB_[6] = {4, 6, 6, 6, 4, 4};
  static const int SK[6]  = {2, 4, 2, 1, 1, 1};     // -> 36 K-steps everywhere
  static const int LGS[6] = {1, 2, 1, 0, 0, 0};

  int abase[6]; { int a = 0; for (int s = 0; s < 6; ++s) { abase[s] = a; a += NB_[s] * HH[s] * HH[s]; } }

  // ws layout: [xh 0..5][wp 0..5][zeros 8KB][ybuf 0..5 bf16]  (~90 MB total)
  size_t xh_off[6], wp_off[6], yb_off[6], off = 0;
  auto al = [](size_t v) { return (v + 255) & ~(size_t)255; };
  for (int s = 0; s < 6; ++s) { xh_off[s] = off; off = al(off + (size_t)8 * HH[s] * HH[s] * CH[s] * 2); }
  for (int s = 0; s < 6; ++s) {
    wp_off[s] = off;
    int Npad = ((NB_[s] * 85 + 127) / 128) * 128;
    off = al(off + (size_t)Npad * (CH[s] * 9) * 2);
  }
  const size_t zeros_off = off; off = al(off + 8192);
  for (int s = 0; s < 6; ++s) {
    yb_off[s] = off;
    int Npad = ((NB_[s] * 85 + 127) / 128) * 128;
    off = al(off + (size_t)SK[s] * (8 * HH[s] * HH[s]) * Npad * 2);
  }
  (void)ws_size;

  char* ws = (char*)d_ws;
  (void)hipMemsetAsync(ws + zeros_off, 0, 8192, stream);

  // merged prep
  PREP pp; int pxb = 0;
  for (int s = 0; s < 6; ++s) {
    PXs& p = pp.x[s];
    p.x = (const float*)d_in[5 * s + 0];
    p.xh = (unsigned short*)(ws + xh_off[s]);
    p.C = CH[s]; p.HWp = HH[s] * HH[s];
    p.ptiles = (p.HWp + 63) / 64;
    p.boff = pxb;
    pxb += 8 * (CH[s] >> 6) * p.ptiles;
  }
  size_t tb = 0;
  for (int s = 0; s < 6; ++s) {
    PWs& p = pp.w[s];
    p.lw = (const float*)d_in[5 * s + 1];
    p.cw = (const float*)d_in[5 * s + 3];
    p.wp = (unsigned short*)(ws + wp_off[s]);
    p.C = CH[s];
    p.lC = (CH[s] == 1024) ? 10 : (CH[s] == 512 ? 9 : 8);
    p.Nloc = NB_[s] * 4; p.Ntot = NB_[s] * 85;
    p.Npad = ((p.Ntot + 127) / 128) * 128;
    p.Kp = CH[s] * 9;
    p.tbase = tb;
    tb += (size_t)p.Npad * CH[s];
  }
  pp.pxb = pxb;
  const int pwb = (int)((tb + NTH - 1) / NTH);
  hipLaunchKernelGGL(prep_all, dim3(pxb + pwb), dim3(NTH), 0, stream, pp);

  // gemm: uniform 36-step blocks
  AG ag; ag.zeros = ws + zeros_off;
  int G = 0;
  for (int s = 0; s < 6; ++s) {
    SG& g = ag.s[s];
    g.xh = (const unsigned short*)(ws + xh_off[s]);
    g.wp = (const unsigned short*)(ws + wp_off[s]);
    g.yb = (unsigned short*)(ws + yb_off[s]);
    g.H = HH[s]; g.W = HH[s]; g.HWp = HH[s] * HH[s];
    g.C = CH[s];
    g.Cq = CH[s] >> 6;
    g.lCq = (g.Cq == 16) ? 4 : (g.Cq == 8 ? 3 : 2);
    g.Kp = CH[s] * 9;
    g.M = 8 * g.HWp;
    g.Npad = ((NB_[s] * 85 + 127) / 128) * 128;
    g.mtiles = (g.M + 127) / 128;
    g.lgS = LGS[s];
    g.boff = G;
    G += g.mtiles * (g.Npad >> 7) * SK[s];
  }
  ag.gq = G / 8; ag.gr = G % 8;
  hipLaunchKernelGGL(mbox_gemm, dim3(G), dim3(NTH), 0, stream, ag);

  // scatter: one block per 8 ybuf rows (all M divisible by 8)
  SC2 sc; int SB = 0;
  for (int s = 0; s < 6; ++s) {
    SC2s& p = sc.s[s];
    p.yb = (const unsigned short*)(ws + yb_off[s]);
    p.lb = (const float*)d_in[5 * s + 2];
    p.cb = (const float*)d_in[5 * s + 4];
    p.HW = HH[s] * HH[s];
    p.nb = NB_[s];
    p.S = SK[s];
    p.Npad = ((NB_[s] * 85 + 127) / 128) * 128;
    p.M = 8 * p.HW;
    p.abase = abase[s];
    p.boff = SB;
    SB += p.M / MR;
  }
  hipLaunchKernelGGL(mbox_scatter, dim3(SB), dim3(NTH), 0, stream, sc, (float*)d_out);
}

// Round 14
// 134.109 us; speedup vs baseline: 1.0892x; 1.0892x over previous
//
#include <hip/hip_runtime.h>
#include <stdint.h>

// SSD multibox head. Round 14: revert to R12 exactly (best measured total,
// 134.4 us). 512-thread GEMM blocks (8 waves, 2m x 4n, wave tile 64x32,
// acc[4][2], 16x16x32 MFMA — conflict-free under the 16B XOR swizzle),
// overlapped 2-phase double-buffer, QS=36, bf16 ybuf partials, merged prep,
// tile-transpose scatter. R13's 32x32 retile reverted (4-way LDS bank
// conflict: 32 rows over 8 swizzle slots).

#define NTH 256
#define GTH 512
#define ATOT 8732
#define LOCTOT 279424       // 8*8732*4
#define QS 36               // K-steps per block, uniform across scales
#define TOTOUT 5937760      // 8*8732*85
#define MR 8                // ybuf rows per scatter block

typedef short short8 __attribute__((ext_vector_type(8)));
typedef unsigned short ushort8 __attribute__((ext_vector_type(8)));
typedef float f32x4 __attribute__((ext_vector_type(4)));

__device__ __forceinline__ unsigned short f2bf(float f) {
  unsigned u = __float_as_uint(f);
  u += 0x7fffu + ((u >> 16) & 1u);   // RNE
  return (unsigned short)(u >> 16);
}

__device__ __forceinline__ float bf2f(unsigned short b) {
  return __uint_as_float((unsigned)b << 16);
}

__device__ __forceinline__ void gload_lds16(const void* g, void* l) {
  __builtin_amdgcn_global_load_lds(
      (const __attribute__((address_space(1))) unsigned int*)g,
      (__attribute__((address_space(3))) unsigned int*)l, 16, 0, 0);
}

// ---------------- merged prep: x-transpose blocks then w-repack blocks ------
struct PXs { const float* x; unsigned short* xh; int C, HWp, ptiles, boff; };
struct PWs { const float *lw, *cw; unsigned short* wp; int C, lC, Nloc, Ntot, Npad, Kp; size_t tbase; };
struct PREP { PXs x[6]; PWs w[6]; int pxb; };

__global__ __launch_bounds__(NTH) void prep_all(PREP P) {
  __shared__ float T[64][65];
  const int tid = threadIdx.x;
  if ((int)blockIdx.x < P.pxb) {
    const int bid = blockIdx.x;
    int e = 0;
    #pragma unroll
    for (int i = 1; i < 6; ++i) if (bid >= P.x[i].boff) e = i;
    const PXs sp = P.x[e];
    const int local = bid - sp.boff;
    const int p64 = local % sp.ptiles;
    const int t2  = local / sp.ptiles;
    const int Cq  = sp.C >> 6;
    const int c64 = t2 % Cq;
    const int bb  = t2 / Cq;

    const int p0 = p64 << 6;
    const float* xs = sp.x + (size_t)(bb * sp.C + (c64 << 6)) * sp.HWp;
    const int tx = tid & 63, ty = tid >> 6;
    const int p = p0 + tx;
    const bool pok = p < sp.HWp;
    #pragma unroll
    for (int j = 0; j < 16; ++j) {
      int c = ty + (j << 2);
      T[c][tx] = pok ? xs[(size_t)c * sp.HWp + p] : 0.f;
    }
    __syncthreads();
    const int pl = tid >> 2, cs = (tid & 3) << 4;
    const int pg = p0 + pl;
    if (pg < sp.HWp) {
      unsigned short* dst = sp.xh + ((size_t)bb * sp.HWp + pg) * sp.C + (c64 << 6) + cs;
      short8 v0, v1;
      #pragma unroll
      for (int j = 0; j < 8; ++j) {
        v0[j] = (short)f2bf(T[cs + j][pl]);
        v1[j] = (short)f2bf(T[cs + 8 + j][pl]);
      }
      *(short8*)dst = v0;
      *(short8*)(dst + 8) = v1;
    }
  } else {
    const size_t g = (size_t)(blockIdx.x - P.pxb) * NTH + tid;
    int e = 0;
    #pragma unroll
    for (int i = 1; i < 6; ++i) if (g >= P.w[i].tbase) e = i;
    const PWs sp = P.w[e];
    const size_t local = g - sp.tbase;
    const int ci = (int)(local & (size_t)(sp.C - 1));
    const int co = (int)(local >> sp.lC);
    if (co >= sp.Npad) return;
    unsigned short* dst = sp.wp + (size_t)co * sp.Kp + ci;
    if (co >= sp.Ntot) {
      #pragma unroll
      for (int r = 0; r < 9; ++r) dst[(size_t)r * sp.C] = 0;
      return;
    }
    const float* wr = (co < sp.Nloc)
        ? (sp.lw + ((size_t)co * sp.C + ci) * 9)
        : (sp.cw + ((size_t)(co - sp.Nloc) * sp.C + ci) * 9);
    float v[9];
    #pragma unroll
    for (int r = 0; r < 9; ++r) v[r] = wr[r];
    #pragma unroll
    for (int r = 0; r < 9; ++r) dst[(size_t)r * sp.C] = f2bf(v[r]);
  }
}

// ---------------- main GEMM: 512 threads, 8 waves (2m x 4n) -----------------
struct SG {
  const unsigned short *xh, *wp;
  unsigned short* yb;              // [S][M][Npad] bf16 partials
  int H, W, HWp, C, lCq, Cq, Kp, M, Npad, mtiles, lgS, boff;
};
struct AG { SG s[6]; const char* zeros; int gq, gr; };

__global__ __launch_bounds__(GTH) void mbox_gemm(AG P) {
  __shared__ __align__(16) unsigned short A_s[2][128 * 64];
  __shared__ __align__(16) unsigned short B_s[2][128 * 64];

  const int bid = blockIdx.x;
  const int xcd = bid & 7, sidx = bid >> 3;
  const int g = (xcd < P.gr) ? xcd * (P.gq + 1) + sidx
                             : P.gr * (P.gq + 1) + (xcd - P.gr) * P.gq + sidx;

  int e = 0;
  #pragma unroll
  for (int i = 1; i < 6; ++i) if (g >= P.s[i].boff) e = i;
  const SG sp = P.s[e];
  const int gl = g - sp.boff;
  const int ks = gl & ((1 << sp.lgS) - 1);
  const int t2 = gl >> sp.lgS;
  const int mtile = t2 % sp.mtiles;
  const int ntile = t2 / sp.mtiles;

  const int tid = threadIdx.x, lane = tid & 63, wv = tid >> 6;   // wv 0..7
  const int wm = wv >> 2, wn = wv & 3;       // 2m x 4n wave grid
  const int swz = ((lane & 7) ^ (lane >> 3)) << 4;
  const int rsub = lane >> 3;

  // A-row geometry: 2 rows per thread (wave stages 16 A-rows + 16 B-rows)
  int bA[2], hA[2], wA[2]; bool mok[2];
  #pragma unroll
  for (int i = 0; i < 2; ++i) {
    int row = (wv << 4) + (i << 3) + rsub;
    int mg = mtile * 128 + row;
    bool ok = mg < sp.M;
    int mc = ok ? mg : 0;
    int bb = mc / sp.HWp; int p = mc - bb * sp.HWp;
    int hh = p / sp.W;    int ww = p - hh * sp.W;
    bA[i] = bb; hA[i] = hh; wA[i] = ww; mok[i] = ok;
  }

  const int q0 = ks * QS, q1 = q0 + QS;

  const char* curB[2];
  #pragma unroll
  for (int i = 0; i < 2; ++i) {
    int row = (wv << 4) + (i << 3) + rsub;
    int nrow = ntile * 128 + row;
    curB[i] = (const char*)(sp.wp + (size_t)nrow * sp.Kp + (size_t)q0 * 64) + swz;
  }

  const char* curA[2];
  auto setA = [&](int rr, int cq0) {
    int d3 = rr / 3; int dh = d3 - 1, dw = rr - d3 * 3 - 1;
    #pragma unroll
    for (int i = 0; i < 2; ++i) {
      int hh = hA[i] + dh, ww = wA[i] + dw;
      bool ok = mok[i] & ((unsigned)hh < (unsigned)sp.H) & ((unsigned)ww < (unsigned)sp.W);
      const unsigned short* base = ok
          ? sp.xh + (((size_t)bA[i] * sp.H + hh) * sp.W + ww) * sp.C + (cq0 << 6)
          : (const unsigned short*)P.zeros;
      curA[i] = (const char*)base + swz;
    }
  };

  auto stage = [&](int buf) {
    char* As = (char*)&A_s[buf][0];
    char* Bs = (char*)&B_s[buf][0];
    #pragma unroll
    for (int i = 0; i < 2; ++i)
      gload_lds16(curA[i], As + ((wv << 4) + (i << 3)) * 128);
    #pragma unroll
    for (int i = 0; i < 2; ++i)
      gload_lds16(curB[i], Bs + ((wv << 4) + (i << 3)) * 128);
  };

  f32x4 acc[4][2] = {};
  const int l15 = lane & 15, lh = lane >> 4;

  setA(q0 >> sp.lCq, q0 & (sp.Cq - 1));
  stage(0);
  #pragma unroll
  for (int i = 0; i < 2; ++i) { curA[i] += 128; curB[i] += 128; }

  int cur = 0;
  for (int q = q0; q < q1; ++q) {
    __syncthreads();
    if (q + 1 < q1) {
      if (((q + 1) & (sp.Cq - 1)) == 0) setA((q + 1) >> sp.lCq, 0);
      stage(cur ^ 1);
      #pragma unroll
      for (int i = 0; i < 2; ++i) { curA[i] += 128; curB[i] += 128; }
    }
    const char* As = (const char*)&A_s[cur][0];
    const char* Bs = (const char*)&B_s[cur][0];
    #pragma unroll
    for (int kk = 0; kk < 2; ++kk) {
      const int klb = ((kk << 5) + (lh << 3)) << 1;
      short8 af[4], bv[2];
      #pragma unroll
      for (int mf = 0; mf < 4; ++mf) {
        int row = (wm << 6) + (mf << 4) + l15;
        af[mf] = *(const short8*)(As + row * 128 + (klb ^ ((row & 7) << 4)));
      }
      #pragma unroll
      for (int nf = 0; nf < 2; ++nf) {
        int row = (wn << 5) + (nf << 4) + l15;
        bv[nf] = *(const short8*)(Bs + row * 128 + (klb ^ ((row & 7) << 4)));
      }
      #pragma unroll
      for (int mf = 0; mf < 4; ++mf)
        #pragma unroll
        for (int nf = 0; nf < 2; ++nf)
          acc[mf][nf] = __builtin_amdgcn_mfma_f32_16x16x32_bf16(af[mf], bv[nf], acc[mf][nf], 0, 0, 0);
    }
    cur ^= 1;
  }

  // epilogue: dense coalesced bf16 store of partial tile into ybuf[ks]
  unsigned short* yb = sp.yb + (size_t)ks * sp.M * sp.Npad;
  #pragma unroll
  for (int nf = 0; nf < 2; ++nf) {
    const int ncol = ntile * 128 + (wn << 5) + (nf << 4) + l15;
    #pragma unroll
    for (int mf = 0; mf < 4; ++mf) {
      #pragma unroll
      for (int rg = 0; rg < 4; ++rg) {
        const int mg = mtile * 128 + (wm << 6) + (mf << 4) + (lh << 2) + rg;
        if (mg < sp.M) yb[(size_t)mg * sp.Npad + ncol] = f2bf(acc[mf][nf][rg]);
      }
    }
  }
}

// ---------------- scatter: tile-staged transpose (bf16 partials) ------------
struct SC2s { const unsigned short* yb; const float *lb, *cb; int HW, nb, S, Npad, M, abase, boff; };
struct SC2 { SC2s s[6]; };

__global__ __launch_bounds__(NTH) void mbox_scatter(SC2 P, float* __restrict__ out) {
  __shared__ float T[MR * 512];     // summed tile, row stride = Npad (<=512)
  __shared__ float LB[32], CB[512];
  const int bid = blockIdx.x;
  int e = 0;
  #pragma unroll
  for (int i = 1; i < 6; ++i) if (bid >= P.s[i].boff) e = i;
  const SC2s sp = P.s[e];
  const int m0 = (bid - sp.boff) * MR;
  const int tid = threadIdx.x;
  const int HW = sp.HW, nb = sp.nb, Npad = sp.Npad;
  const int nb4v = nb * 4;

  for (int i = tid; i < nb4v; i += NTH) LB[i] = sp.lb[i];
  for (int i = tid; i < nb * 81; i += NTH) CB[i] = sp.cb[i];

  const int np8 = Npad >> 3;
  const int tot8 = MR * np8;
  const size_t dstride8 = (size_t)sp.M * np8;      // in ushort8 units
  const ushort8* yb8 = (const ushort8*)sp.yb + (size_t)m0 * np8;
  for (int idx = tid; idx < tot8; idx += NTH) {
    float v[8] = {0.f, 0.f, 0.f, 0.f, 0.f, 0.f, 0.f, 0.f};
    const ushort8* p = yb8 + idx;
    for (int k = 0; k < sp.S; ++k) {
      ushort8 w = *p; p += dstride8;
      #pragma unroll
      for (int j = 0; j < 8; ++j) v[j] += bf2f(w[j]);
    }
    #pragma unroll
    for (int j = 0; j < 8; ++j) T[(idx << 3) + j] = v[j];
  }
  __syncthreads();

  if (tid < MR * nb) {
    const int mloc = tid / nb, rb = tid - (tid / nb) * nb;
    const int m = m0 + mloc;
    const int b = m / HW, p = m - b * HW;
    const int aidx = sp.abase + rb * HW + p;
    float4 v;
    #pragma unroll
    for (int ii = 0; ii < 4; ++ii)
      (&v.x)[ii] = T[mloc * Npad + ii * nb + rb] + LB[ii * nb + rb];
    ((float4*)out)[(size_t)b * ATOT + aidx] = v;
  }

  const int totc = MR * nb * 81;
  float* outc = out + LOCTOT;
  for (int f = tid; f < totc; f += NTH) {
    const int ii = f % 81;
    const int gg = f / 81;
    const int rb = gg % nb;
    const int mloc = gg / nb;
    const int m = m0 + mloc;
    const int b = m / HW, p = m - b * HW;
    const int aidx = sp.abase + rb * HW + p;
    const int c = ii * nb + rb;
    outc[((size_t)b * ATOT + aidx) * 81 + ii] = T[mloc * Npad + nb4v + c] + CB[c];
  }
}

// ---------------- host ------------------------------------------------------
extern "C" void kernel_launch(void* const* d_in, const int* in_sizes, int n_in,
                              void* d_out, int out_size, void* d_ws, size_t ws_size,
                              hipStream_t stream) {
  static const int CH[6]  = {512, 1024, 512, 256, 256, 256};
  static const int HH[6]  = {38, 19, 10, 5, 3, 1};
  static const int NB_[6] = {4, 6, 6, 6, 4, 4};
  static const int SK[6]  = {2, 4, 2, 1, 1, 1};     // -> 36 K-steps everywhere
  static const int LGS[6] = {1, 2, 1, 0, 0, 0};

  int abase[6]; { int a = 0; for (int s = 0; s < 6; ++s) { abase[s] = a; a += NB_[s] * HH[s] * HH[s]; } }

  // ws layout: [xh 0..5][wp 0..5][zeros 8KB][ybuf 0..5 bf16]  (~90 MB total)
  size_t xh_off[6], wp_off[6], yb_off[6], off = 0;
  auto al = [](size_t v) { return (v + 255) & ~(size_t)255; };
  for (int s = 0; s < 6; ++s) { xh_off[s] = off; off = al(off + (size_t)8 * HH[s] * HH[s] * CH[s] * 2); }
  for (int s = 0; s < 6; ++s) {
    wp_off[s] = off;
    int Npad = ((NB_[s] * 85 + 127) / 128) * 128;
    off = al(off + (size_t)Npad * (CH[s] * 9) * 2);
  }
  const size_t zeros_off = off; off = al(off + 8192);
  for (int s = 0; s < 6; ++s) {
    yb_off[s] = off;
    int Npad = ((NB_[s] * 85 + 127) / 128) * 128;
    off = al(off + (size_t)SK[s] * (8 * HH[s] * HH[s]) * Npad * 2);
  }
  (void)ws_size;

  char* ws = (char*)d_ws;
  (void)hipMemsetAsync(ws + zeros_off, 0, 8192, stream);

  // merged prep
  PREP pp; int pxb = 0;
  for (int s = 0; s < 6; ++s) {
    PXs& p = pp.x[s];
    p.x = (const float*)d_in[5 * s + 0];
    p.xh = (unsigned short*)(ws + xh_off[s]);
    p.C = CH[s]; p.HWp = HH[s] * HH[s];
    p.ptiles = (p.HWp + 63) / 64;
    p.boff = pxb;
    pxb += 8 * (CH[s] >> 6) * p.ptiles;
  }
  size_t tb = 0;
  for (int s = 0; s < 6; ++s) {
    PWs& p = pp.w[s];
    p.lw = (const float*)d_in[5 * s + 1];
    p.cw = (const float*)d_in[5 * s + 3];
    p.wp = (unsigned short*)(ws + wp_off[s]);
    p.C = CH[s];
    p.lC = (CH[s] == 1024) ? 10 : (CH[s] == 512 ? 9 : 8);
    p.Nloc = NB_[s] * 4; p.Ntot = NB_[s] * 85;
    p.Npad = ((p.Ntot + 127) / 128) * 128;
    p.Kp = CH[s] * 9;
    p.tbase = tb;
    tb += (size_t)p.Npad * CH[s];
  }
  pp.pxb = pxb;
  const int pwb = (int)((tb + NTH - 1) / NTH);
  hipLaunchKernelGGL(prep_all, dim3(pxb + pwb), dim3(NTH), 0, stream, pp);

  // gemm: uniform 36-step blocks, 512 threads
  AG ag; ag.zeros = ws + zeros_off;
  int G = 0;
  for (int s = 0; s < 6; ++s) {
    SG& g = ag.s[s];
    g.xh = (const unsigned short*)(ws + xh_off[s]);
    g.wp = (const unsigned short*)(ws + wp_off[s]);
    g.yb = (unsigned short*)(ws + yb_off[s]);
    g.H = HH[s]; g.W = HH[s]; g.HWp = HH[s] * HH[s];
    g.C = CH[s];
    g.Cq = CH[s] >> 6;
    g.lCq = (g.Cq == 16) ? 4 : (g.Cq == 8 ? 3 : 2);
    g.Kp = CH[s] * 9;
    g.M = 8 * g.HWp;
    g.Npad = ((NB_[s] * 85 + 127) / 128) * 128;
    g.mtiles = (g.M + 127) / 128;
    g.lgS = LGS[s];
    g.boff = G;
    G += g.mtiles * (g.Npad >> 7) * SK[s];
  }
  ag.gq = G / 8; ag.gr = G % 8;
  hipLaunchKernelGGL(mbox_gemm, dim3(G), dim3(GTH), 0, stream, ag);

  // scatter: one block per 8 ybuf rows (all M divisible by 8)
  SC2 sc; int SB = 0;
  for (int s = 0; s < 6; ++s) {
    SC2s& p = sc.s[s];
    p.yb = (const unsigned short*)(ws + yb_off[s]);
    p.lb = (const float*)d_in[5 * s + 2];
    p.cb = (const float*)d_in[5 * s + 4];
    p.HW = HH[s] * HH[s];
    p.nb = NB_[s];
    p.S = SK[s];
    p.Npad = ((NB_[s] * 85 + 127) / 128) * 128;
    p.M = 8 * p.HW;
    p.abase = abase[s];
    p.boff = SB;
    SB += p.M / MR;
  }
  hipLaunchKernelGGL(mbox_scatter, dim3(SB), dim3(NTH), 0, stream, sc, (float*)d_out);
}